// Round 1
// baseline (1069.733 us; speedup 1.0000x reference)
//
#include <hip/hip_runtime.h>

#define D_DIM 512
#define H_DIM 512
#define G_SEG 1024
#define BM    128

typedef __attribute__((ext_vector_type(8))) short bf16x8;
typedef __attribute__((ext_vector_type(4))) float f32x4;

// Dynamic LDS layout:
//   As:    128 rows x 512 bf16, row stride 1024B, XOR-swizzled (byte ^= (row&7)<<4)  131072 B
//   Bs:    128 rows x 72 bf16 (64 + 8 pad), stride 144B                               18432 B
//   betaP: 2 x 128 f32                                                                 1024 B
//   ebs:   128 f32                                                                      512 B
//   sidx:  128 i32                                                                      512 B
#define AS_OFF    0
#define AS_BYTES  (BM * 1024)
#define BS_OFF    AS_BYTES
#define BS_STRIDE 144
#define BS_BYTES  (128 * BS_STRIDE)
#define BETA_OFF  (BS_OFF + BS_BYTES)
#define EBS_OFF   (BETA_OFF + 2 * BM * 4)
#define SIDX_OFF  (EBS_OFF + BM * 4)
#define LDS_TOTAL (SIDX_OFF + BM * 4)

static __device__ __forceinline__ unsigned short f2bf(float f) {
    unsigned int u = __float_as_uint(f);
    u += 0x7fffu + ((u >> 16) & 1u);   // round-to-nearest-even
    return (unsigned short)(u >> 16);
}
static __device__ __forceinline__ float bf2f(unsigned int bits) {
    return __uint_as_float(bits << 16);
}

__global__ __launch_bounds__(256, 1)
void attn_fused(const float* __restrict__ E, const int* __restrict__ BI,
                const float* __restrict__ W, const float* __restrict__ V,
                float* __restrict__ outRaw, float* __restrict__ S)
{
    extern __shared__ char smem[];
    const int tid = threadIdx.x;
    const int nodeBase = blockIdx.x * BM;

    // ---- stage the full 128x512 embed tile fp32 -> bf16, swizzled ----
    {
        const float* Eb = E + ((size_t)nodeBase << 9);
        for (int it = 0; it < 64; ++it) {
            int idx = it * 256 + tid;       // float4 index, 16384 total
            int row = idx >> 7;             // 128 float4 per row
            int d   = (idx & 127) << 2;
            float4 f = *(const float4*)(Eb + ((size_t)row << 9) + d);
            ushort4 h;
            h.x = f2bf(f.x); h.y = f2bf(f.y); h.z = f2bf(f.z); h.w = f2bf(f.w);
            int byte = row * 1024 + ((d << 1) ^ ((row & 7) << 4));
            *(ushort4*)(smem + AS_OFF + byte) = h;
        }
    }
    __syncthreads();

    const int l   = tid & 63;
    const int w   = tid >> 6;
    const int wr  = w >> 1;     // 2 row-groups of 64 rows
    const int wc  = w & 1;      // 2 col-groups of 64 cols
    const int l15 = l & 15;
    const int lhi = l >> 4;

    float bsum[4][4];
#pragma unroll
    for (int m = 0; m < 4; ++m)
#pragma unroll
        for (int r = 0; r < 4; ++r) bsum[m][r] = 0.f;

    for (int ns = 0; ns < 4; ++ns) {        // 4 column-stages of 128 h each
        f32x4 acc[4][4];
#pragma unroll
        for (int m = 0; m < 4; ++m)
#pragma unroll
            for (int n = 0; n < 4; ++n) acc[m][n] = (f32x4){0.f, 0.f, 0.f, 0.f};

        for (int ks = 0; ks < 8; ++ks) {    // K steps of 64
            __syncthreads();
            {   // stage Bs[c][kk] = bf16(W[ns*128+c][ks*64+kk])
                const float* Wb = W + ((size_t)(ns * 128) << 9) + ks * 64;
#pragma unroll
                for (int it = 0; it < 8; ++it) {
                    int idx = it * 256 + tid;      // 2048 float4
                    int c  = idx >> 4;
                    int kk = (idx & 15) << 2;
                    float4 f = *(const float4*)(Wb + ((size_t)c << 9) + kk);
                    ushort4 h;
                    h.x = f2bf(f.x); h.y = f2bf(f.y); h.z = f2bf(f.z); h.w = f2bf(f.w);
                    *(ushort4*)(smem + BS_OFF + c * BS_STRIDE + (kk << 1)) = h;
                }
            }
            __syncthreads();
#pragma unroll
            for (int ksub = 0; ksub < 2; ++ksub) {
                const int kg = ks * 64 + ksub * 32 + lhi * 8;
                bf16x8 a[4], b[4];
#pragma unroll
                for (int m = 0; m < 4; ++m) {
                    int row = wr * 64 + m * 16 + l15;
                    int byte = row * 1024 + ((kg << 1) ^ ((row & 7) << 4));
                    a[m] = *(const bf16x8*)(smem + AS_OFF + byte);
                }
                const int kk = ksub * 32 + lhi * 8;
#pragma unroll
                for (int n = 0; n < 4; ++n) {
                    int c = wc * 64 + n * 16 + l15;
                    b[n] = *(const bf16x8*)(smem + BS_OFF + c * BS_STRIDE + (kk << 1));
                }
#pragma unroll
                for (int m = 0; m < 4; ++m)
#pragma unroll
                    for (int n = 0; n < 4; ++n)
                        acc[m][n] = __builtin_amdgcn_mfma_f32_16x16x32_bf16(a[m], b[n], acc[m][n], 0, 0, 0);
            }
        }
        // epilogue for this column stage: bsum += sum_cols V*tanh(z)
        float Vv[4];
#pragma unroll
        for (int n = 0; n < 4; ++n)
            Vv[n] = V[ns * 128 + wc * 64 + n * 16 + l15];
#pragma unroll
        for (int m = 0; m < 4; ++m)
#pragma unroll
            for (int r = 0; r < 4; ++r) {
                float p = 0.f;
#pragma unroll
                for (int n = 0; n < 4; ++n)
                    p += Vv[n] * tanhf(acc[m][n][r]);
                bsum[m][r] += p;
            }
    }

    // reduce over the 16 column-lanes (bits 0..3 of lane id)
#pragma unroll
    for (int off = 1; off <= 8; off <<= 1)
#pragma unroll
        for (int m = 0; m < 4; ++m)
#pragma unroll
            for (int r = 0; r < 4; ++r)
                bsum[m][r] += __shfl_xor(bsum[m][r], off, 64);

    float* betaP = (float*)(smem + BETA_OFF);
    if (l15 == 0) {
#pragma unroll
        for (int m = 0; m < 4; ++m)
#pragma unroll
            for (int r = 0; r < 4; ++r)
                betaP[wc * BM + wr * 64 + m * 16 + lhi * 4 + r] = bsum[m][r];
    }
    __syncthreads();

    float* ebs  = (float*)(smem + EBS_OFF);
    int*   sidx = (int*)(smem + SIDX_OFF);
    if (tid < BM) {
        float beta = betaP[tid] + betaP[BM + tid];
        float eb = expf(beta);
        ebs[tid] = eb;
        int g = BI[nodeBase + tid];
        sidx[tid] = g;
        atomicAdd(&S[g], eb);
    }
    __syncthreads();

    // weighted segment accumulation: out_raw[g][d] += eb * embed (bf16 from LDS)
    const int d0 = tid << 1;
    float a0 = 0.f, a1 = 0.f;
    int gcur = sidx[0];
    for (int row = 0; row < BM; ++row) {
        int g = sidx[row];                       // uniform across threads
        if (g != gcur) {
            atomicAdd(&outRaw[gcur * D_DIM + d0],     a0);
            atomicAdd(&outRaw[gcur * D_DIM + d0 + 1], a1);
            a0 = 0.f; a1 = 0.f; gcur = g;
        }
        float eb = ebs[row];
        int byte = row * 1024 + ((d0 << 1) ^ ((row & 7) << 4));
        unsigned int pk = *(const unsigned int*)(smem + AS_OFF + byte);
        a0 += eb * bf2f(pk & 0xffffu);
        a1 += eb * bf2f(pk >> 16);
    }
    atomicAdd(&outRaw[gcur * D_DIM + d0],     a0);
    atomicAdd(&outRaw[gcur * D_DIM + d0 + 1], a1);
}

__global__ void finalize_kernel(float* __restrict__ out, const float* __restrict__ S) {
    int idx = blockIdx.x * 256 + threadIdx.x;
    float s = S[idx >> 9];                 // idx/512 = segment
    float v = out[idx];
    out[idx] = (s != 0.f) ? v / s : 0.f;
}

extern "C" void kernel_launch(void* const* d_in, const int* in_sizes, int n_in,
                              void* d_out, int out_size, void* d_ws, size_t ws_size,
                              hipStream_t stream) {
    const float* E  = (const float*)d_in[0];
    const int*   BI = (const int*)d_in[1];
    const float* W  = (const float*)d_in[2];
    const float* V  = (const float*)d_in[3];
    float* out = (float*)d_out;
    float* S   = (float*)d_ws;
    const int Ntot = in_sizes[0] / D_DIM;

    hipMemsetAsync(out, 0, (size_t)out_size * sizeof(float), stream);
    hipMemsetAsync(S, 0, G_SEG * sizeof(float), stream);
    hipFuncSetAttribute((const void*)attn_fused,
                        hipFuncAttributeMaxDynamicSharedMemorySize, LDS_TOTAL);

    attn_fused<<<Ntot / BM, 256, LDS_TOTAL, stream>>>(E, BI, W, V, out, S);
    finalize_kernel<<<out_size / 256, 256, 0, stream>>>(out, S);
}

// Round 2
// 463.396 us; speedup vs baseline: 2.3085x; 2.3085x over previous
//
#include <hip/hip_runtime.h>
#include <hip/hip_bf16.h>

#define D_DIM 512
#define H_DIM 512
#define G_SEG 1024

typedef __attribute__((ext_vector_type(8))) short bf16x8;
typedef __attribute__((ext_vector_type(4))) float f32x4;
typedef unsigned int u32;
typedef unsigned short u16;

// ---- workspace layout (bytes) ----
#define WS_BETA  0                         // N f32   (1 MB)
#define WS_EBS   (1u << 20)                // N f32   (1 MB)
#define WS_S     (2u << 20)                // G f32   (4 KB)
#define WS_WSWZ  ((2u << 20) + 8192u)      // 512 KB pre-swizzled bf16 W
#define WS_E16   (3u << 20)                // N*512 bf16 (256 MB) if ws allows

#define GLOBAL_AS __attribute__((address_space(1)))
#define LDS_AS    __attribute__((address_space(3)))

static __device__ __forceinline__ void gload_lds16(const void* g, void* l) {
    __builtin_amdgcn_global_load_lds((const GLOBAL_AS u32*)g, (LDS_AS u32*)l, 16, 0, 0);
}
static __device__ __forceinline__ u16 f2bf(float f) {
    __hip_bfloat16 h = __float2bfloat16(f);   // RNE; compiler fuses pairs to v_cvt_pk_bf16_f32
    return *(u16*)&h;
}
static __device__ __forceinline__ float bf2f(u16 u) {
    return __uint_as_float(((u32)u) << 16);
}
static __device__ __forceinline__ float fast_tanh(float x) {
    float e = exp2f(x * 2.885390081777927f);      // e^(2x)
    return 1.0f - 2.0f * __builtin_amdgcn_rcpf(e + 1.0f);
}

// ---- W fp32 -> bf16, tiled [jn(4)][ks(8)][c(128)][k(64)], chunk-swizzled ----
// LDS-linear copy of a (jn,ks) tile then yields Bs[c][j*16B] == W[c][ (j^(c&7)) chunk ]
__global__ __launch_bounds__(256)
void cvt_w(const float* __restrict__ W, u16* __restrict__ Wswz) {
    int t  = blockIdx.x * 256 + threadIdx.x;   // 32768 threads, 8 bf16 each
    int j  = t & 7;
    int c  = (t >> 3) & 127;
    int ks = (t >> 10) & 7;
    int jn = t >> 13;
    int jp = j ^ (c & 7);
    const float* src = W + (size_t)(jn * 128 + c) * 512 + ks * 64 + jp * 8;
    float4 f0 = *(const float4*)(src);
    float4 f1 = *(const float4*)(src + 4);
    u16 h[8];
    h[0]=f2bf(f0.x); h[1]=f2bf(f0.y); h[2]=f2bf(f0.z); h[3]=f2bf(f0.w);
    h[4]=f2bf(f1.x); h[5]=f2bf(f1.y); h[6]=f2bf(f1.z); h[7]=f2bf(f1.w);
    u16* dst = Wswz + ((size_t)(jn * 8 + ks) * 128 + c) * 64 + j * 8;
    *(uint4*)dst = *(uint4*)h;
}

// ---- GEMM + tanh + V-reduce -> partial beta ----
// grid 8192: 2048 row-panels (128 nodes) x 4 col-panels (128 H).
// XCD-swizzled so the 4 col-panels of one row-panel share an XCD.
__global__ __launch_bounds__(256, 3)
void gemm_beta(const float* __restrict__ E, const float* __restrict__ V,
               const u16* __restrict__ Wswz, float* __restrict__ betaAcc,
               u16* __restrict__ E16, int storeE16)
{
    __shared__ u16 As[128 * 64];   // row stride 128B, XOR-swizzled
    __shared__ u16 Bs[128 * 64];   // row stride 128B, swizzle baked into Wswz

    const int tid = threadIdx.x;
    const int bid = blockIdx.x;
    const int xcd = bid & 7;
    const int jn  = (bid >> 3) & 3;
    const int im  = xcd + ((bid >> 5) << 3);

    const int l   = tid & 63;
    const int w   = tid >> 6;
    const int wr  = w >> 1;
    const int wc  = w & 1;
    const int l15 = l & 15;
    const int lhi = l >> 4;

    const float* Ebase = E + (size_t)im * 128 * 512;
    const u16*   Wtile = Wswz + (size_t)jn * 8 * (128 * 64);

    f32x4 acc[4][4];
#pragma unroll
    for (int m = 0; m < 4; ++m)
#pragma unroll
        for (int n = 0; n < 4; ++n) acc[m][n] = (f32x4){0.f, 0.f, 0.f, 0.f};

    float4 aload[8];
    // prologue: global loads for ks=0
#pragma unroll
    for (int it = 0; it < 8; ++it) {
        int idx = it * 256 + tid, row = idx >> 4, j = idx & 15;
        aload[it] = *(const float4*)(Ebase + (size_t)row * 512 + j * 4);
    }

    for (int ks = 0; ks < 8; ++ks) {
        // ---- stage ks from regs: cvt -> swizzled ds_write (+ E16 store), B via gload_lds
#pragma unroll
        for (int it = 0; it < 8; ++it) {
            int idx = it * 256 + tid, row = idx >> 4, j = idx & 15;
            ushort4 h;
            h.x = f2bf(aload[it].x); h.y = f2bf(aload[it].y);
            h.z = f2bf(aload[it].z); h.w = f2bf(aload[it].w);
            int byte = row * 128 + ((j * 8) ^ ((row & 7) << 4));
            *(ushort4*)((char*)As + byte) = h;
            if (storeE16 && jn == 0)
                *(ushort4*)(E16 + (size_t)(im * 128 + row) * 512 + ks * 64 + j * 4) = h;
        }
#pragma unroll
        for (int i = 0; i < 4; ++i) {
            int off = (w * 4 + i) * 1024 + l * 16;   // bytes
            gload_lds16((const char*)(Wtile + (size_t)ks * 128 * 64) + off, (char*)Bs + off);
        }
        __syncthreads();

        // ---- issue next-k global loads before compute (latency hides under MFMA)
        if (ks < 7) {
#pragma unroll
            for (int it = 0; it < 8; ++it) {
                int idx = it * 256 + tid, row = idx >> 4, j = idx & 15;
                aload[it] = *(const float4*)(Ebase + (size_t)row * 512 + (ks + 1) * 64 + j * 4);
            }
        }

        // ---- compute: 2 ksub x 16 MFMA
#pragma unroll
        for (int ksub = 0; ksub < 2; ++ksub) {
            const int kbyte = ksub * 64 + lhi * 16;
            bf16x8 a[4], b[4];
#pragma unroll
            for (int m = 0; m < 4; ++m) {
                int row = wr * 64 + m * 16 + l15;
                a[m] = *(const bf16x8*)((const char*)As + row * 128 + (kbyte ^ ((row & 7) << 4)));
            }
#pragma unroll
            for (int n = 0; n < 4; ++n) {
                int c = wc * 64 + n * 16 + l15;
                b[n] = *(const bf16x8*)((const char*)Bs + c * 128 + (kbyte ^ ((c & 7) << 4)));
            }
#pragma unroll
            for (int m = 0; m < 4; ++m)
#pragma unroll
                for (int n = 0; n < 4; ++n)
                    acc[m][n] = __builtin_amdgcn_mfma_f32_16x16x32_bf16(a[m], b[n], acc[m][n], 0, 0, 0);
        }
        __syncthreads();
    }

    // ---- epilogue: beta partial = sum_cols V * tanh(z)
    float Vv[4];
#pragma unroll
    for (int n = 0; n < 4; ++n)
        Vv[n] = V[jn * 128 + wc * 64 + n * 16 + l15];

    float bsum[4][4];
#pragma unroll
    for (int m = 0; m < 4; ++m)
#pragma unroll
        for (int r = 0; r < 4; ++r) {
            float s = 0.f;
#pragma unroll
            for (int n = 0; n < 4; ++n)
                s += Vv[n] * fast_tanh(acc[m][n][r]);
            bsum[m][r] = s;
        }
#pragma unroll
    for (int off = 1; off <= 8; off <<= 1)
#pragma unroll
        for (int m = 0; m < 4; ++m)
#pragma unroll
            for (int r = 0; r < 4; ++r)
                bsum[m][r] += __shfl_xor(bsum[m][r], off, 64);

    if (l15 == 0) {
#pragma unroll
        for (int m = 0; m < 4; ++m)
#pragma unroll
            for (int r = 0; r < 4; ++r)
                atomicAdd(&betaAcc[im * 128 + wr * 64 + m * 16 + lhi * 4 + r], bsum[m][r]);
    }
}

// ---- eb = exp(beta); S[g] += eb (wave-aggregated when segment uniform) ----
__global__ __launch_bounds__(256)
void eb_kernel(const float* __restrict__ betaAcc, const int* __restrict__ BI,
               float* __restrict__ ebs, float* __restrict__ S)
{
    int n = blockIdx.x * 256 + threadIdx.x;
    float eb = expf(betaAcc[n]);
    ebs[n] = eb;
    int g = BI[n];
    int g0 = __shfl(g, 0, 64);
    if (__all(g == g0)) {
        float s = eb;
#pragma unroll
        for (int off = 1; off <= 32; off <<= 1)
            s += __shfl_xor(s, off, 64);
        if ((threadIdx.x & 63) == 0) atomicAdd(&S[g], s);
    } else {
        atomicAdd(&S[g], eb);
    }
}

// ---- out[g][d] += (eb/S[g]) * E[n][d]  (normalization folded in) ----
template <bool BF16SRC>
__global__ __launch_bounds__(256)
void wsum(const u16* __restrict__ E16, const float* __restrict__ Ef,
          const int* __restrict__ BI, const float* __restrict__ ebs,
          const float* __restrict__ S, float* __restrict__ out)
{
    __shared__ float al[256];
    __shared__ int   sg[256];
    const int t = threadIdx.x;
    const int base = blockIdx.x * 256;
    {
        int n = base + t;
        int g = BI[n];
        sg[t] = g;
        al[t] = ebs[n] * __builtin_amdgcn_rcpf(S[g]);
    }
    __syncthreads();

    const int c4 = (t & 127) * 4;     // 4 cols, 16B(f32)/8B(bf16) per lane
    const int rg = t >> 7;            // 2 row groups, stride 2
    float a0 = 0.f, a1 = 0.f, a2 = 0.f, a3 = 0.f;
    int gcur = sg[rg];
    for (int r = rg; r < 256; r += 2) {
        int g = sg[r];
        if (g != gcur) {
            float* o = out + (size_t)gcur * 512 + c4;
            atomicAdd(o, a0); atomicAdd(o + 1, a1); atomicAdd(o + 2, a2); atomicAdd(o + 3, a3);
            a0 = a1 = a2 = a3 = 0.f; gcur = g;
        }
        float wgt = al[r];
        if (BF16SRC) {
            ushort4 v = *(const ushort4*)(E16 + (size_t)(base + r) * 512 + c4);
            a0 += wgt * bf2f(v.x); a1 += wgt * bf2f(v.y);
            a2 += wgt * bf2f(v.z); a3 += wgt * bf2f(v.w);
        } else {
            float4 v = *(const float4*)(Ef + (size_t)(base + r) * 512 + c4);
            a0 += wgt * v.x; a1 += wgt * v.y; a2 += wgt * v.z; a3 += wgt * v.w;
        }
    }
    float* o = out + (size_t)gcur * 512 + c4;
    atomicAdd(o, a0); atomicAdd(o + 1, a1); atomicAdd(o + 2, a2); atomicAdd(o + 3, a3);
}

extern "C" void kernel_launch(void* const* d_in, const int* in_sizes, int n_in,
                              void* d_out, int out_size, void* d_ws, size_t ws_size,
                              hipStream_t stream) {
    const float* E  = (const float*)d_in[0];
    const int*   BI = (const int*)d_in[1];
    const float* W  = (const float*)d_in[2];
    const float* V  = (const float*)d_in[3];
    float* out = (float*)d_out;
    char*  ws  = (char*)d_ws;
    const int Ntot = in_sizes[0] / D_DIM;

    float* betaAcc = (float*)(ws + WS_BETA);
    float* ebs     = (float*)(ws + WS_EBS);
    float* S       = (float*)(ws + WS_S);
    u16*   Wswz    = (u16*)(ws + WS_WSWZ);
    u16*   E16     = (u16*)(ws + WS_E16);
    const bool useE16 = ws_size >= (size_t)WS_E16 + (size_t)Ntot * D_DIM * 2;

    hipMemsetAsync(betaAcc, 0, (size_t)Ntot * 4, stream);
    hipMemsetAsync(S, 0, G_SEG * 4, stream);
    hipMemsetAsync(out, 0, (size_t)out_size * 4, stream);

    cvt_w<<<128, 256, 0, stream>>>(W, Wswz);
    gemm_beta<<<(Ntot / 128) * 4, 256, 0, stream>>>(E, V, Wswz, betaAcc, E16, useE16 ? 1 : 0);
    eb_kernel<<<Ntot / 256, 256, 0, stream>>>(betaAcc, BI, ebs, S);
    if (useE16)
        wsum<true><<<Ntot / 256, 256, 0, stream>>>(E16, nullptr, BI, ebs, S, out);
    else
        wsum<false><<<Ntot / 256, 256, 0, stream>>>(nullptr, E, BI, ebs, S, out);
}

// Round 3
// 371.053 us; speedup vs baseline: 2.8830x; 1.2489x over previous
//
#include <hip/hip_runtime.h>
#include <hip/hip_bf16.h>

#define D_DIM 512
#define H_DIM 512
#define G_SEG 1024
#define BM    128

typedef __attribute__((ext_vector_type(8))) short bf16x8;
typedef __attribute__((ext_vector_type(4))) float f32x4;
typedef unsigned int u32;
typedef unsigned short u16;

// ---- workspace ----
#define WS_S   0         // G f32
#define WS_WB  8192      // 512 KB bf16 W in MFMA-fragment granule layout

// ---- LDS ----  As: 128 rows x 1024B (bf16 x 512, XOR-swizzled)
#define AS_BYTES  (128 * 1024)
#define BETA_OFF  AS_BYTES
#define EBS_OFF   (BETA_OFF + 4 * 128 * 4)
#define SIDX_OFF  (EBS_OFF + 128 * 4)
#define LDS_TOTAL (SIDX_OFF + 128 * 4)

static __device__ __forceinline__ u16 f2bf(float f) {
    __hip_bfloat16 h = __float2bfloat16(f);
    return *(u16*)&h;
}
static __device__ __forceinline__ float bf2f(u16 u) {
    return __uint_as_float(((u32)u) << 16);
}
static __device__ __forceinline__ float fast_tanh(float x) {
    float e = exp2f(x * 2.885390081777927f);   // e^(2x)
    return 1.0f - 2.0f * __builtin_amdgcn_rcpf(e + 1.0f);
}

// ---- W fp32 -> bf16 in granule layout: granule(k32, c, lhi) = W[c][k32*32 + lhi*8 .. +8]
// byte offset = ((k32*512 + c)*4 + lhi)*16
__global__ __launch_bounds__(256)
void cvt_w(const float* __restrict__ W, u16* __restrict__ Wb) {
    int t   = blockIdx.x * 256 + threadIdx.x;   // 32768 granules
    int lhi = t & 3;
    int c   = (t >> 2) & 511;
    int k32 = t >> 11;
    const float* src = W + (size_t)c * 512 + k32 * 32 + lhi * 8;
    float4 f0 = *(const float4*)(src);
    float4 f1 = *(const float4*)(src + 4);
    u16 h[8];
    h[0]=f2bf(f0.x); h[1]=f2bf(f0.y); h[2]=f2bf(f0.z); h[3]=f2bf(f0.w);
    h[4]=f2bf(f1.x); h[5]=f2bf(f1.y); h[6]=f2bf(f1.z); h[7]=f2bf(f1.w);
    *(uint4*)(Wb + (size_t)t * 8) = *(uint4*)h;
}

// ---- fused: GEMM(128 x 512 x 512) + tanh*V reduce + exp + segment sums ----
__global__ __launch_bounds__(512, 2)
void fused(const float* __restrict__ E, const int* __restrict__ BI,
           const u16* __restrict__ Wb, const float* __restrict__ V,
           float* __restrict__ out, float* __restrict__ S)
{
    extern __shared__ char smem[];
    const int tid = threadIdx.x;
    const int nodeBase = blockIdx.x * BM;
    const int l   = tid & 63;
    const int w   = tid >> 6;
    const int wr  = w >> 2;       // 2 row groups (64 rows)
    const int wc  = w & 3;        // 4 col groups (128 cols)
    const int l15 = l & 15;
    const int lhi = l >> 4;

    const float* Eb = E + (size_t)nodeBase * 512;
    const int arow = tid >> 3;    // 0..63, second row = arow+64
    const int aj   = tid & 7;

    f32x4 acc[4][8];
#pragma unroll
    for (int m = 0; m < 4; ++m)
#pragma unroll
        for (int n = 0; n < 8; ++n) acc[m][n] = (f32x4){0.f, 0.f, 0.f, 0.f};

    float4 aload[4];
    {   // prologue loads for ks=0
        const float* p0 = Eb + (size_t)arow * 512 + aj * 8;
        aload[0] = *(const float4*)p0;       aload[1] = *(const float4*)(p0 + 4);
        const float* p1 = p0 + 64 * 512;
        aload[2] = *(const float4*)p1;       aload[3] = *(const float4*)(p1 + 4);
    }

    for (int ks = 0; ks < 8; ++ks) {
        // ---- stage A slab ks: cvt fp32->bf16, swizzled 16B writes
        {
            u16 h[8];
            h[0]=f2bf(aload[0].x); h[1]=f2bf(aload[0].y); h[2]=f2bf(aload[0].z); h[3]=f2bf(aload[0].w);
            h[4]=f2bf(aload[1].x); h[5]=f2bf(aload[1].y); h[6]=f2bf(aload[1].z); h[7]=f2bf(aload[1].w);
            int byte0 = arow * 1024 + ((ks * 128 + aj * 16) ^ ((arow & 7) << 4));
            *(uint4*)(smem + byte0) = *(uint4*)h;
            h[0]=f2bf(aload[2].x); h[1]=f2bf(aload[2].y); h[2]=f2bf(aload[2].z); h[3]=f2bf(aload[2].w);
            h[4]=f2bf(aload[3].x); h[5]=f2bf(aload[3].y); h[6]=f2bf(aload[3].z); h[7]=f2bf(aload[3].w);
            *(uint4*)(smem + byte0 + 64 * 1024) = *(uint4*)h;
        }
        // ---- prefetch next slab's E while this kstep computes
        if (ks < 7) {
            const float* p0 = Eb + (size_t)arow * 512 + (ks + 1) * 64 + aj * 8;
            aload[0] = *(const float4*)p0;   aload[1] = *(const float4*)(p0 + 4);
            const float* p1 = p0 + 64 * 512;
            aload[2] = *(const float4*)p1;   aload[3] = *(const float4*)(p1 + 4);
        }
        __syncthreads();

        // ---- compute: B frags straight from L2-resident Wb, A frags from LDS
#pragma unroll
        for (int ksub = 0; ksub < 2; ++ksub) {
            const char* Wsub = (const char*)Wb + ((size_t)(ks * 2 + ksub) << 15);
            bf16x8 b[8];
#pragma unroll
            for (int n = 0; n < 8; ++n) {
                int c = wc * 128 + n * 16 + l15;
                b[n] = *(const bf16x8*)(Wsub + (c * 4 + lhi) * 16);
            }
            bf16x8 a[4];
            const int kbyte = ks * 128 + ksub * 64 + lhi * 16;
#pragma unroll
            for (int m = 0; m < 4; ++m) {
                int row = wr * 64 + m * 16 + l15;
                a[m] = *(const bf16x8*)(smem + row * 1024 + (kbyte ^ ((row & 7) << 4)));
            }
#pragma unroll
            for (int m = 0; m < 4; ++m)
#pragma unroll
                for (int n = 0; n < 8; ++n)
                    acc[m][n] = __builtin_amdgcn_mfma_f32_16x16x32_bf16(a[m], b[n], acc[m][n], 0, 0, 0);
        }
        // no trailing barrier: next iteration writes a DIFFERENT 16KB slab
    }

    // ---- epilogue: beta = sum_h V[h] * tanh(z[:,h])
    float Vv[8];
#pragma unroll
    for (int n = 0; n < 8; ++n)
        Vv[n] = V[wc * 128 + n * 16 + l15];

    float bsum[4][4];
#pragma unroll
    for (int m = 0; m < 4; ++m)
#pragma unroll
        for (int r = 0; r < 4; ++r) {
            float s = 0.f;
#pragma unroll
            for (int n = 0; n < 8; ++n)
                s += Vv[n] * fast_tanh(acc[m][n][r]);
            bsum[m][r] = s;
        }
#pragma unroll
    for (int off = 1; off <= 8; off <<= 1)
#pragma unroll
        for (int m = 0; m < 4; ++m)
#pragma unroll
            for (int r = 0; r < 4; ++r)
                bsum[m][r] += __shfl_xor(bsum[m][r], off, 64);

    float* betaP = (float*)(smem + BETA_OFF);
    if (l15 == 0) {
#pragma unroll
        for (int m = 0; m < 4; ++m)
#pragma unroll
            for (int r = 0; r < 4; ++r)
                betaP[wc * 128 + wr * 64 + m * 16 + lhi * 4 + r] = bsum[m][r];
    }
    __syncthreads();

    // ---- eb = exp(beta); S[g] += eb (wave-aggregated; rows sorted)
    float* ebs  = (float*)(smem + EBS_OFF);
    int*   sidx = (int*)(smem + SIDX_OFF);
    if (tid < 128) {
        float beta = betaP[tid] + betaP[128 + tid] + betaP[256 + tid] + betaP[384 + tid];
        float eb = expf(beta);
        ebs[tid] = eb;
        int g = BI[nodeBase + tid];
        sidx[tid] = g;
        int g0 = __shfl(g, 0, 64);
        if (__all(g == g0)) {
            float s = eb;
#pragma unroll
            for (int off = 1; off <= 32; off <<= 1)
                s += __shfl_xor(s, off, 64);
            if (l == 0) atomicAdd(&S[g], s);
        } else {
            atomicAdd(&S[g], eb);
        }
    }
    __syncthreads();

    // ---- weighted segment sum from LDS bf16 tile: out[g][c] += eb[r]*A[r][c]
    const int c = tid;     // 512 cols
    float a = 0.f;
    int gcur = sidx[0];
    for (int r = 0; r < 128; ++r) {
        int g = sidx[r];                      // uniform across the wave
        if (g != gcur) {
            atomicAdd(&out[(size_t)gcur * 512 + c], a);
            a = 0.f; gcur = g;
        }
        u16 v = *(const u16*)(smem + r * 1024 + ((2 * c) ^ ((r & 7) << 4)));
        a += ebs[r] * bf2f(v);
    }
    atomicAdd(&out[(size_t)gcur * 512 + c], a);
}

__global__ __launch_bounds__(256)
void finalize_kernel(float* __restrict__ out, const float* __restrict__ S) {
    int idx = blockIdx.x * 256 + threadIdx.x;
    float s = S[idx >> 9];
    float v = out[idx];
    out[idx] = (s != 0.f) ? v * __builtin_amdgcn_rcpf(s) : 0.f;
}

extern "C" void kernel_launch(void* const* d_in, const int* in_sizes, int n_in,
                              void* d_out, int out_size, void* d_ws, size_t ws_size,
                              hipStream_t stream) {
    const float* E  = (const float*)d_in[0];
    const int*   BI = (const int*)d_in[1];
    const float* W  = (const float*)d_in[2];
    const float* V  = (const float*)d_in[3];
    float* out = (float*)d_out;
    char*  ws  = (char*)d_ws;
    const int Ntot = in_sizes[0] / D_DIM;

    float* S  = (float*)(ws + WS_S);
    u16*   Wb = (u16*)(ws + WS_WB);

    hipMemsetAsync(S, 0, G_SEG * 4, stream);
    hipMemsetAsync(out, 0, (size_t)out_size * 4, stream);
    hipFuncSetAttribute((const void*)fused,
                        hipFuncAttributeMaxDynamicSharedMemorySize, LDS_TOTAL);

    cvt_w<<<128, 256, 0, stream>>>(W, Wb);
    fused<<<Ntot / BM, 512, LDS_TOTAL, stream>>>(E, BI, Wb, V, out, S);
    finalize_kernel<<<out_size / 256, 256, 0, stream>>>(out, S);
}